// Round 1
// baseline (1575.396 us; speedup 1.0000x reference)
//
#include <hip/hip_runtime.h>
#include <math.h>

namespace {

constexpr int TNZ = 8, TNY = 512, TNX = 512, TNM = 4, TM = 128;
constexpr int PITCH = 130;                 // float2 pitch of LDS field (even -> 16B-aligned float4 rows)
constexpr float F0 = 1.0f / (TM * 0.2f);   // fftfreq step 1/(M*dr)
constexpr float PK = -3.14159265358979323846f * 0.025f * 10.0f;  // -pi*lambda*dz
constexpr float INV_N2 = 1.0f / (TM * TM);
constexpr float EPSV = 1e-10f;

__device__ __forceinline__ float2 cmul(float2 a, float2 b) {
  return make_float2(a.x * b.x - a.y * b.y, a.x * b.y + a.y * b.x);
}

// ---- local (in-thread) radix-2 stages; twd[m] = exp(-2*pi*i*m/128), m<64 ----
template<int H>
__device__ __forceinline__ void dif_local(float2 (&X)[32], const float2* twd) {
#pragma unroll
  for (int m = 0; m < H; ++m) {
    float2 W = twd[m * (64 / H)];
#pragma unroll
    for (int b = 0; b < 32; b += 2 * H) {
      const int j = b + m;
      float2 A = X[j], B = X[j + H];
      X[j] = make_float2(A.x + B.x, A.y + B.y);
      float2 d = make_float2(A.x - B.x, A.y - B.y);
      X[j + H] = cmul(d, W);
    }
  }
}

template<int H>
__device__ __forceinline__ void dit_local(float2 (&X)[32], const float2* twd) {
#pragma unroll
  for (int m = 0; m < H; ++m) {
    float2 W = twd[m * (64 / H)];
#pragma unroll
    for (int b = 0; b < 32; b += 2 * H) {
      const int j = b + m;
      float2 A = X[j], B0 = X[j + H];
      // B = B0 * conj(W)
      float2 B = make_float2(B0.x * W.x + B0.y * W.y, B0.y * W.x - B0.x * W.y);
      X[j] = make_float2(A.x + B.x, A.y + B.y);
      X[j + H] = make_float2(A.x - B.x, A.y - B.y);
    }
  }
}

// Forward DIF FFT-128, thread s (0..3) owns n = 32*s + j (natural in, bitrev positions out)
__device__ __forceinline__ void dif128(float2 (&X)[32], const float2* twd, int s) {
  const bool up2 = (s & 2) != 0;
  const bool odd = (s & 1) != 0;
  // stage h=64, partner lane ^2 ; W = twd[32*(s&1)+j] = twd[j] * (odd ? -i : 1)
#pragma unroll
  for (int j = 0; j < 32; ++j) {
    float2 o = make_float2(__shfl_xor(X[j].x, 2, 64), __shfl_xor(X[j].y, 2, 64));
    float2 tw = twd[j];
    float2 W = odd ? make_float2(tw.y, -tw.x) : tw;
    float2 sum = make_float2(X[j].x + o.x, X[j].y + o.y);
    float2 dif = make_float2(o.x - X[j].x, o.y - X[j].y);
    float2 pr = cmul(dif, W);
    X[j] = up2 ? pr : sum;
  }
  // stage h=32, partner ^1 ; W = twd[2j] (wave-uniform)
#pragma unroll
  for (int j = 0; j < 32; ++j) {
    float2 o = make_float2(__shfl_xor(X[j].x, 1, 64), __shfl_xor(X[j].y, 1, 64));
    float2 W = twd[2 * j];
    float2 sum = make_float2(X[j].x + o.x, X[j].y + o.y);
    float2 dif = make_float2(o.x - X[j].x, o.y - X[j].y);
    float2 pr = cmul(dif, W);
    X[j] = odd ? pr : sum;
  }
  dif_local<16>(X, twd);
  dif_local<8>(X, twd);
  dif_local<4>(X, twd);
  dif_local<2>(X, twd);
#pragma unroll
  for (int b = 0; b < 32; b += 2) {  // h=1, W=1
    float2 A = X[b], B = X[b + 1];
    X[b] = make_float2(A.x + B.x, A.y + B.y);
    X[b + 1] = make_float2(A.x - B.x, A.y - B.y);
  }
}

// Inverse (DIT) FFT-128: exact inverse network of dif128 (bitrev in, natural out, unscaled)
__device__ __forceinline__ void dit128(float2 (&X)[32], const float2* twd, int s) {
  const bool up2 = (s & 2) != 0;
  const bool odd = (s & 1) != 0;
#pragma unroll
  for (int b = 0; b < 32; b += 2) {  // h=1
    float2 A = X[b], B = X[b + 1];
    X[b] = make_float2(A.x + B.x, A.y + B.y);
    X[b + 1] = make_float2(A.x - B.x, A.y - B.y);
  }
  dit_local<2>(X, twd);
  dit_local<4>(X, twd);
  dit_local<8>(X, twd);
  dit_local<16>(X, twd);
  // cross h=32, partner ^1 : lower: u + v*conjW ; upper: u - v*conjW
  {
    const float sg = odd ? -1.0f : 1.0f;
#pragma unroll
    for (int j = 0; j < 32; ++j) {
      float2 o = make_float2(__shfl_xor(X[j].x, 1, 64), __shfl_xor(X[j].y, 1, 64));
      float2 tw = twd[2 * j];
      float2 in = odd ? X[j] : o;   // the upper element's value
      float2 ot = odd ? o : X[j];   // the lower element's value
      float2 B = make_float2(in.x * tw.x + in.y * tw.y, in.y * tw.x - in.x * tw.y);
      X[j] = make_float2(fmaf(sg, B.x, ot.x), fmaf(sg, B.y, ot.y));
    }
  }
  // cross h=64, partner ^2 : conjW = conj(twd[j] * (odd ? -i : 1))
  {
    const float sg = up2 ? -1.0f : 1.0f;
#pragma unroll
    for (int j = 0; j < 32; ++j) {
      float2 o = make_float2(__shfl_xor(X[j].x, 2, 64), __shfl_xor(X[j].y, 2, 64));
      float2 tw = twd[j];
      float2 cW = odd ? make_float2(tw.y, tw.x) : make_float2(tw.x, -tw.y);
      float2 in = up2 ? X[j] : o;
      float2 ot = up2 ? o : X[j];
      float2 B = cmul(in, cW);
      X[j] = make_float2(fmaf(sg, B.x, ot.x), fmaf(sg, B.y, ot.y));
    }
  }
}

__global__ __launch_bounds__(512, 2) void msp_fwd(
    const float* __restrict__ V, const float* __restrict__ Pre,
    const float* __restrict__ Pim, const int* __restrict__ pos,
    float* __restrict__ out) {
  __shared__ float2 fld[TM * PITCH];   // 133,120 B transpose buffer
  __shared__ float2 twd[64];

  const int t = threadIdx.x;
  const int k = blockIdx.x;
  const int s = t & 3;       // segment within a row/col (owns x = 32*s + j)
  const int rc = t >> 2;     // row (row passes) / col (col passes), 0..127

  if (t < 64) {
    float ang = -2.0f * 3.14159265358979323846f * (float)t / 128.0f;
    twd[t] = make_float2(cosf(ang), sinf(ang));
  }
  __syncthreads();

  const int p0 = pos[2 * k];
  const int p1 = pos[2 * k + 1];

  // per-thread H constants: kx = bitrev7(rc)
  const int kx = ((rc & 1) << 6) | ((rc & 2) << 4) | ((rc & 4) << 2) | (rc & 8) |
                 ((rc & 16) >> 2) | ((rc & 32) >> 4) | ((rc & 64) >> 6);
  const int ixf = kx - ((kx & 64) ? 128 : 0);
  const float fx2 = (ixf * F0) * (ixf * F0);
  const int rev2s = ((s & 1) << 1) | (s >> 1);

  float acc[32];
#pragma unroll
  for (int j = 0; j < 32; ++j) acc[j] = 0.0f;

  float2 X[32];

  for (int m = 0; m < TNM; ++m) {
    // load probe mode m (row ownership)
    {
      const float4* pr = reinterpret_cast<const float4*>(Pre + ((m * TM + rc) * TM + 32 * s));
      const float4* pi = reinterpret_cast<const float4*>(Pim + ((m * TM + rc) * TM + 32 * s));
#pragma unroll
      for (int q = 0; q < 8; ++q) {
        float4 a = pr[q], b = pi[q];
        X[4 * q + 0] = make_float2(a.x, b.x);
        X[4 * q + 1] = make_float2(a.y, b.y);
        X[4 * q + 2] = make_float2(a.z, b.z);
        X[4 * q + 3] = make_float2(a.w, b.w);
      }
    }

    for (int z = 0; z < TNZ; ++z) {
      // multiply by T = exp(i*V) at patch (p0+row, p1+x)
      {
        const float* vb = V + ((z * TNY + (p0 + rc)) * TNX + p1 + 32 * s);
#pragma unroll
        for (int j = 0; j < 32; ++j) {
          float v = vb[j];
          X[j] = cmul(X[j], make_float2(__cosf(v), __sinf(v)));
        }
      }
      dif128(X, twd, s);            // rows
      // transpose rows -> cols
      __syncthreads();
      {
        float4* dst = reinterpret_cast<float4*>(&fld[rc * PITCH + 32 * s]);
#pragma unroll
        for (int q = 0; q < 16; ++q)
          dst[q] = make_float4(X[2 * q].x, X[2 * q].y, X[2 * q + 1].x, X[2 * q + 1].y);
      }
      __syncthreads();
#pragma unroll
      for (int j = 0; j < 32; ++j) X[j] = fld[(32 * s + j) * PITCH + rc];

      dif128(X, twd, s);            // cols

      if (z == TNZ - 1) break;      // last slice: no propagation

      // H multiply at (ky=bitrev(32s+j), kx=bitrev(rc)); fold 1/N^2 of the ifft2
#pragma unroll
      for (int j = 0; j < 32; ++j) {
        const int r5 = ((j & 1) << 4) | ((j & 2) << 2) | (j & 4) | ((j & 8) >> 2) | ((j & 16) >> 4);
        const int ky = 4 * r5 + rev2s;
        const int iy = ky - ((ky & 64) ? 128 : 0);
        const float fy = iy * F0;
        const float ph = PK * (fy * fy + fx2);
        float2 w = make_float2(__cosf(ph) * INV_N2, __sinf(ph) * INV_N2);
        X[j] = cmul(X[j], w);
      }

      dit128(X, twd, s);            // cols inverse
      // transpose cols -> rows
      __syncthreads();
#pragma unroll
      for (int j = 0; j < 32; ++j) fld[(32 * s + j) * PITCH + rc] = X[j];
      __syncthreads();
      {
        const float4* src = reinterpret_cast<const float4*>(&fld[rc * PITCH + 32 * s]);
#pragma unroll
        for (int q = 0; q < 16; ++q) {
          float4 a = src[q];
          X[2 * q] = make_float2(a.x, a.y);
          X[2 * q + 1] = make_float2(a.z, a.w);
        }
      }
      dit128(X, twd, s);            // rows inverse
    }

    // accumulate |psi_f|^2 (unnormalized)
#pragma unroll
    for (int j = 0; j < 32; ++j)
      acc[j] = fmaf(X[j].x, X[j].x, fmaf(X[j].y, X[j].y, acc[j]));
  }

  // un-bit-reverse via LDS, then coalesced global write of amp
  __syncthreads();
  float* fldf = reinterpret_cast<float*>(fld);
#pragma unroll
  for (int j = 0; j < 32; ++j) {
    const int r5 = ((j & 1) << 4) | ((j & 2) << 2) | (j & 4) | ((j & 8) >> 2) | ((j & 16) >> 4);
    const int ky = 4 * r5 + rev2s;
    fldf[ky * PITCH + kx] = acc[j];
  }
  __syncthreads();
  float* ob = out + k * (TM * TM);
#pragma unroll
  for (int i = 0; i < 32; ++i) {
    const int idx = t + 512 * i;
    const int yy = idx >> 7, xx = idx & 127;
    const float a = fldf[yy * PITCH + xx];
    ob[idx] = sqrtf(EPSV + a * INV_N2);   // ortho norm: 1/128 per fft2 -> 1/16384 on |.|^2
  }
}

}  // namespace

extern "C" void kernel_launch(void* const* d_in, const int* in_sizes, int n_in,
                              void* d_out, int out_size, void* d_ws, size_t ws_size,
                              hipStream_t stream) {
  (void)in_sizes; (void)n_in; (void)out_size; (void)d_ws; (void)ws_size;
  const float* V = (const float*)d_in[0];
  const float* Pre = (const float*)d_in[1];
  const float* Pim = (const float*)d_in[2];
  const int* pos = (const int*)d_in[3];
  float* out = (float*)d_out;
  msp_fwd<<<dim3(256), dim3(512), 0, stream>>>(V, Pre, Pim, pos, out);
}